// Round 4
// baseline (342.061 us; speedup 1.0000x reference)
//
#include <hip/hip_runtime.h>
#include <math.h>

// Fastfood layer, round 7: one (row, m) pair per wave -- max TLP.
//
// Rounds 5/6 post-mortem: kernel never shows in rocprof top-5 (< 164 us;
// dur_us includes a ~167 us harness fill).  The kernel's own ~168 us is ~3x
// its VALU floor because 3-4 resident waves/SIMD can't hide the per-m chain
// latency, and ILP-2 traded occupancy for ILP ~1:1.  This round goes the
// other way: each wave handles ONE (row, m) pair.
//   - 65536 waves, ~70 live VGPRs -> ~7 waves/SIMD resident (vs 3-4),
//   - per-wave serial chain is 16x shorter; table-load latency sits at wave
//     start where other waves' compute covers it,
//   - mapping row = gw>>3, m = gw&7: a block's 4 waves share one x-row
//     (L1 hits), the adjacent block reuses it via L2.  x loads are now
//     CACHED (re-read 8x per row); out stores stay nontemporal.
//
// FWHT-1024, all in registers (per wave):
//   bits 0-3 : reg-index butterflies
//   bits 4-7 : lane bits 0-3 via DPP (xor1=B1, xor2=4E, xor4=HMIR.1B, xor8=ror8)
//   bit 8    : v_permlane16_swap pair trick (swap, +/-, swap)
//   bit 9    : v_permlane32_swap pair trick
// LDS only for the permutation staging: 4x ds_write_b128 + 16 ds_read_b32
// per wave.  Padding addr(i) = i + 4*(i>>6); per-wave slices, no barriers.
// FWHT#1 in natural layout (i = 16*lane + k); gather reads P/G at L2'
// positions (i' = 256*b + 4*lane + c) so FWHT#2 runs in the L2' layout
// (stages commute) and the epilogue is fully contiguous float4.

typedef unsigned uint2_ev __attribute__((ext_vector_type(2)));
typedef float    f32x4    __attribute__((ext_vector_type(4)));

template <int CTRL>
__device__ __forceinline__ float dpp_f(float x) {
    return __int_as_float(
        __builtin_amdgcn_mov_dpp(__float_as_int(x), CTRL, 0xF, 0xF, true));
}

#define DPP_XOR1 0xB1   // quad_perm [1,0,3,2]
#define DPP_XOR2 0x4E   // quad_perm [2,3,0,1]
#define DPP_XOR3 0x1B   // quad_perm [3,2,1,0]
#define DPP_HMIR 0x141  // row_half_mirror: lane ^ 7
#define DPP_ROR8 0x128  // row_ror:8 == lane ^ 8

// One permlane16_swap butterfly step on a register pair.
__device__ __forceinline__ void pl16_pair(float& e0, float& e1) {
    uint2_ev r = __builtin_amdgcn_permlane16_swap(
        __float_as_uint(e0), __float_as_uint(e1), false, false);
    float s = __uint_as_float(r.x) + __uint_as_float(r.y);
    float d = __uint_as_float(r.x) - __uint_as_float(r.y);
    uint2_ev q = __builtin_amdgcn_permlane16_swap(
        __float_as_uint(s), __float_as_uint(d), false, false);
    e0 = __uint_as_float(q.x);
    e1 = __uint_as_float(q.y);
}

__device__ __forceinline__ void pl32_pair(float& e0, float& e1) {
    uint2_ev r = __builtin_amdgcn_permlane32_swap(
        __float_as_uint(e0), __float_as_uint(e1), false, false);
    float s = __uint_as_float(r.x) + __uint_as_float(r.y);
    float d = __uint_as_float(r.x) - __uint_as_float(r.y);
    uint2_ev q = __builtin_amdgcn_permlane32_swap(
        __float_as_uint(s), __float_as_uint(d), false, false);
    e0 = __uint_as_float(q.x);
    e1 = __uint_as_float(q.y);
}

// Full 10-stage FWHT-1024, zero LDS traffic.
__device__ __forceinline__ void fwht_full(float v[16], float sg0, float sg1,
                                          float sg2, float sg3) {
    // reg-index bits (4 stages)
#pragma unroll
    for (int h = 1; h < 16; h <<= 1) {
#pragma unroll
        for (int k = 0; k < 16; ++k) {
            if (!(k & h)) {
                float a = v[k], b = v[k ^ h];
                v[k] = a + b;
                v[k ^ h] = a - b;
            }
        }
    }
    // lane bits 0-3 via DPP: new = partner + sg*v
#pragma unroll
    for (int k = 0; k < 16; ++k) v[k] = fmaf(v[k], sg0, dpp_f<DPP_XOR1>(v[k]));
#pragma unroll
    for (int k = 0; k < 16; ++k) v[k] = fmaf(v[k], sg1, dpp_f<DPP_XOR2>(v[k]));
#pragma unroll
    for (int k = 0; k < 16; ++k)
        v[k] = fmaf(v[k], sg2, dpp_f<DPP_XOR3>(dpp_f<DPP_HMIR>(v[k])));
#pragma unroll
    for (int k = 0; k < 16; ++k) v[k] = fmaf(v[k], sg3, dpp_f<DPP_ROR8>(v[k]));
    // lane bit 4 (lane ^ 16) and bit 5 (lane ^ 32): pair tricks
#pragma unroll
    for (int p = 0; p < 8; ++p) pl16_pair(v[2 * p], v[2 * p + 1]);
#pragma unroll
    for (int p = 0; p < 8; ++p) pl32_pair(v[2 * p], v[2 * p + 1]);
}

__global__ __launch_bounds__(256) void fastfood_kernel(
    const float* __restrict__ x, const float* __restrict__ B,
    const float* __restrict__ G, const float* __restrict__ S,
    const int* __restrict__ P, const float* __restrict__ u_rand,
    float* __restrict__ out)
{
    __shared__ float lds[4 * 1088];           // 4 waves * padded 1024
    const int lane = threadIdx.x & 63;
    const int wv   = threadIdx.x >> 6;
    const int gw   = blockIdx.x * 4 + wv;     // global wave id
    const int row  = gw >> 3;                 // 8192 rows
    const int mo   = (gw & 7) << 10;          // m * 1024

    const float sg0 = (lane & 1) ? -1.f : 1.f;
    const float sg1 = (lane & 2) ? -1.f : 1.f;
    const float sg2 = (lane & 4) ? -1.f : 1.f;
    const float sg3 = (lane & 8) ? -1.f : 1.f;

    float* wlds = lds + wv * 1088;
    // natural-layout padded write base: addr(16L+4j+c) = i + 4*(i>>6)
    float4* w4 = (float4*)(wlds + 16 * lane + 4 * (lane >> 2));

    const float c_arg = 0.03125f * 0.15915494309189535f;  // (1/32)*(1/2pi)
    const float c_amp = 0.015625f;                        // sqrt(2/8192)

    float v[16];

    // v = x[row] * B[m]  (natural layout; x CACHED -- re-read by 8 waves)
    {
        const float4* x4 = (const float4*)(x + (size_t)row * 1024 + 16 * lane);
        const float4* B4 = (const float4*)(B + mo + 16 * lane);
#pragma unroll
        for (int j = 0; j < 4; ++j) {
            float4 xt = x4[j];
            float4 bt = B4[j];
            v[4 * j + 0] = xt.x * bt.x;
            v[4 * j + 1] = xt.y * bt.y;
            v[4 * j + 2] = xt.z * bt.z;
            v[4 * j + 3] = xt.w * bt.w;
        }
    }

    // ---- FWHT #1, fully in registers ----
    fwht_full(v, sg0, sg1, sg2, sg3);

    // P/G loads issued before the staging writes (independent; L2 latency
    // overlaps the LDS round trip).
    const int4*   P4 = (const int4*)(P + mo);
    const float4* G4 = (const float4*)(G + mo);
    int4   pj[4];
    float4 gj[4];
#pragma unroll
    for (int j = 0; j < 4; ++j) {
        pj[j] = P4[64 * j + lane];
        gj[j] = G4[64 * j + lane];
    }

    // Staging write for the gather (natural positions, 4x b128)
#pragma unroll
    for (int j = 0; j < 4; ++j)
        w4[j] = make_float4(v[4 * j + 0], v[4 * j + 1],
                            v[4 * j + 2], v[4 * j + 3]);

    // Random gather at L2' positions (i' = 256j + 4*lane + c) * G.
#pragma unroll
    for (int j = 0; j < 4; ++j) {
        int4 p = pj[j];
        float4 g = gj[j];
        v[4 * j + 0] = wlds[p.x + ((p.x >> 6) << 2)] * g.x;
        v[4 * j + 1] = wlds[p.y + ((p.y >> 6) << 2)] * g.y;
        v[4 * j + 2] = wlds[p.z + ((p.z >> 6) << 2)] * g.z;
        v[4 * j + 3] = wlds[p.w + ((p.w >> 6) << 2)] * g.w;
    }

    // S/u loads issued here so their latency hides under FWHT #2.
    float4 sv[4], uv[4];
    {
        const float4* S4 = (const float4*)(S + mo);
        const float4* U4 = (const float4*)(u_rand + mo);
#pragma unroll
        for (int b = 0; b < 4; ++b) {
            int idx = b * 64 + lane;
            sv[b] = S4[idx];
            uv[b] = U4[idx];
        }
    }

    // ---- FWHT #2, fully in registers (L2' layout, stages commute) ----
    fwht_full(v, sg0, sg1, sg2, sg3);

    // Epilogue in L2': element i = b*256 + 4*lane + c -> float4 idx b*64+lane
    {
        f32x4* o4 = (f32x4*)(out + (size_t)row * 8192 + mo);
#pragma unroll
        for (int b = 0; b < 4; ++b) {
            int idx = b * 64 + lane;
            f32x4 rr;
            rr.x = __builtin_amdgcn_cosf(__builtin_amdgcn_fractf(
                       fmaf(v[4 * b + 0] * sv[b].x, c_arg, uv[b].x))) * c_amp;
            rr.y = __builtin_amdgcn_cosf(__builtin_amdgcn_fractf(
                       fmaf(v[4 * b + 1] * sv[b].y, c_arg, uv[b].y))) * c_amp;
            rr.z = __builtin_amdgcn_cosf(__builtin_amdgcn_fractf(
                       fmaf(v[4 * b + 2] * sv[b].z, c_arg, uv[b].z))) * c_amp;
            rr.w = __builtin_amdgcn_cosf(__builtin_amdgcn_fractf(
                       fmaf(v[4 * b + 3] * sv[b].w, c_arg, uv[b].w))) * c_amp;
            __builtin_nontemporal_store(rr, &o4[idx]);
        }
    }
}

extern "C" void kernel_launch(void* const* d_in, const int* in_sizes, int n_in,
                              void* d_out, int out_size, void* d_ws, size_t ws_size,
                              hipStream_t stream) {
    const float* x = (const float*)d_in[0];
    const float* B = (const float*)d_in[1];
    const float* G = (const float*)d_in[2];
    const float* S = (const float*)d_in[3];
    const int*   P = (const int*)d_in[4];
    const float* u = (const float*)d_in[5];
    float* out = (float*)d_out;

    dim3 grid(16384), block(256);
    hipLaunchKernelGGL(fastfood_kernel, grid, block, 0, stream,
                       x, B, G, S, P, u, out);
}